// Round 7
// baseline (5450.994 us; speedup 1.0000x reference)
//
#include <hip/hip_runtime.h>
#include <hip/hip_bf16.h>

__device__ __forceinline__ float lrelu(float v){ return v >= 0.f ? v : 0.1f*v; }

// Dims: B=4, C=64, H=W=160, HW=25600, per-tensor (B,64,160,160) f32: batch stride 1,638,400 elems
// ws: 4 f32 slots x 26,214,400 B (A, Bv, T1, T2) + part/part2/mu/Weff tail. branchH lives in d_out.

// ---------------- spa: per-view 3x3 conv (zero pad at view edges) ----------
// grid (B*25, 8 cogroups of 8), block 256. Zero-bordered LDS plane, float4 staging, no bounds checks.
__global__ __launch_bounds__(256) void k_spa(const float* __restrict__ buf1, const float* __restrict__ w,
                                             float* __restrict__ out){
  const int b = blockIdx.x / 25, view = blockIdx.x % 25;
  const int bi = view / 5, bj = view % 5;
  const int cog = blockIdx.y;
  const int tid = threadIdx.x;
  __shared__ float plane[34*40];   // row stride 40; interior rows 1..32, cols 4..35; border stays 0
  __shared__ float wl[72];
  for (int idx=tid; idx<34*40; idx+=256) plane[idx]=0.f;
  float acc[4][8];
  #pragma unroll
  for (int k=0;k<4;k++)
    #pragma unroll
    for (int c=0;c<8;c++) acc[k][c]=0.f;
  const float* src = buf1 + (size_t)b*1638400 + bi*32*160 + bj*32;
  const int r = tid >> 3, qc = (tid & 7)*4;           // 32 rows x 8 quads = 256 float4
  for (int ci=0; ci<64; ci++){
    __syncthreads();
    const float4 v4 = *(const float4*)(src + (size_t)ci*25600 + r*160 + qc);
    *(float4*)&plane[(1+r)*40 + 4 + qc] = v4;
    if (tid < 72) wl[tid] = w[((size_t)(cog*8 + tid/9)*64 + ci)*9 + tid%9];
    __syncthreads();
    #pragma unroll
    for (int k=0;k<4;k++){
      int p = tid + k*256;
      int si = p >> 5, sj = p & 31;
      const float* pp = &plane[si*40 + sj + 3];       // tap (dy,dx) at pp[dy*40+dx]
      float n0=pp[0],  n1=pp[1],  n2=pp[2];
      float n3=pp[40], n4=pp[41], n5=pp[42];
      float n6=pp[80], n7=pp[81], n8=pp[82];
      #pragma unroll
      for (int c=0;c<8;c++){
        const float* wp = &wl[c*9];
        acc[k][c] += n0*wp[0]+n1*wp[1]+n2*wp[2]+n3*wp[3]+n4*wp[4]+n5*wp[5]+n6*wp[6]+n7*wp[7]+n8*wp[8];
      }
    }
  }
  #pragma unroll
  for (int k=0;k<4;k++){
    int p = tid + k*256;
    int si = p >> 5, sj = p & 31;
    int h = si*5 + bi, wq = sj*5 + bj;
    #pragma unroll
    for (int c=0;c<8;c++){
      int ch = b*64 + cog*8 + c;
      out[(size_t)ch*25600 + h*160 + wq] = lrelu(acc[k][c]);
    }
  }
}

// ---------------- ang: per-macropixel (5x5) 3x3 conv ----------------------
// grid (B*32, 8 cogroups of 8), block 256. Guard-row LDS [7][172], v-edges via multipliers.
__global__ __launch_bounds__(256) void k_ang(const float* __restrict__ bufA, const float* __restrict__ w,
                                             float* __restrict__ out){
  const int b = blockIdx.x >> 5, mi = blockIdx.x & 31;
  const int cog = blockIdx.y;
  const int tid = threadIdx.x;
  __shared__ float rowp[7*172];    // rows: image row+1 (rows 0,6 = zero guards); data cols 4..163
  __shared__ float wl[72];
  for (int idx=tid; idx<7*172; idx+=256) rowp[idx]=0.f;
  float acc[4][8];
  #pragma unroll
  for (int k=0;k<4;k++)
    #pragma unroll
    for (int c=0;c<8;c++) acc[k][c]=0.f;
  int pu[4], pbase[4];
  float plm[4], prm[4];
  bool act[4];
  #pragma unroll
  for (int k=0;k<4;k++){
    int p = tid + k*256;
    act[k] = p < 800;
    int pp = act[k] ? p : 0;
    int mp = pp/25; int pos = pp - mp*25;
    int u = pos/5, v = pos - u*5;
    pu[k] = u;
    pbase[k] = 4 + mp*5 + v - 1;
    plm[k] = (v!=0) ? 1.f : 0.f;
    prm[k] = (v!=4) ? 1.f : 0.f;
  }
  const float* src = bufA + (size_t)b*1638400 + mi*800;
  const int sr = tid/40, sq = (tid%40)*4;             // 5 rows x 40 quads = 200 float4
  for (int ci=0; ci<64; ci++){
    __syncthreads();
    if (tid < 200){
      const float4 v4 = *(const float4*)(src + (size_t)ci*25600 + sr*160 + sq);
      *(float4*)&rowp[(1+sr)*172 + 4 + sq] = v4;
    }
    if (tid < 72) wl[tid] = w[((size_t)(cog*8 + tid/9)*64 + ci)*9 + tid%9];
    __syncthreads();
    #pragma unroll
    for (int k=0;k<4;k++){
      if (act[k]){
        const float* pp = &rowp[pu[k]*172 + pbase[k]];
        float lm = plm[k], rm = prm[k];
        float n0=pp[0]*lm,   n1=pp[1],   n2=pp[2]*rm;
        float n3=pp[172]*lm, n4=pp[173], n5=pp[174]*rm;
        float n6=pp[344]*lm, n7=pp[345], n8=pp[346]*rm;
        #pragma unroll
        for (int c=0;c<8;c++){
          const float* wp=&wl[c*9];
          acc[k][c] += n0*wp[0]+n1*wp[1]+n2*wp[2]+n3*wp[3]+n4*wp[4]+n5*wp[5]+n6*wp[6]+n7*wp[7]+n8*wp[8];
        }
      }
    }
  }
  #pragma unroll
  for (int k=0;k<4;k++){
    if (act[k]){
      int p = tid + k*256;
      int mp = p/25; int pos = p - mp*25;
      int u = pos/5, v = pos - u*5;
      int h = mi*5 + u, wq = mp*5 + v;
      #pragma unroll
      for (int c=0;c<8;c++){
        int ch = b*64 + cog*8 + c;
        out[(size_t)ch*25600 + h*160 + wq] = lrelu(acc[k][c]);
      }
    }
  }
}

// ---------------- fused EPI: [1,15]s5p5 conv + lrelu + 1x1 64->320 + shuffle
template<int VERT>
__global__ __launch_bounds__(320) void k_epi(const float* __restrict__ bufA, const float* __restrict__ we1,
                                             const float* __restrict__ we2, float* __restrict__ out){
  const int b = blockIdx.x / 160, hw = blockIdx.x % 160;
  const int tid = threadIdx.x;
  __shared__ float rowp[64*172];   // per ci: [0,5)=0, data [5,165), [165,172)=0
  __shared__ float y1s[64][32];
  for (int idx=tid; idx<64*160; idx+=320){
    int ci = idx/160, x = idx - ci*160;
    size_t gi = (size_t)b*1638400 + (size_t)ci*25600 + (VERT ? (size_t)x*160 + hw : (size_t)hw*160 + x);
    rowp[ci*172 + 5 + x] = bufA[gi];
  }
  for (int idx=tid; idx<64*12; idx+=320){
    int ci=idx/12, j=idx-ci*12;
    rowp[ci*172 + (j<5 ? j : 160+j)] = 0.f;
  }
  __syncthreads();
  if (tid < 256){
    const int co = tid >> 2, wv0 = (tid & 3)*8;
    float acc[8];
    #pragma unroll
    for (int j=0;j<8;j++) acc[j]=0.f;
    const float* wp0 = we1 + (size_t)co*960;
    for (int ci=0; ci<64; ci++){
      const float* wp = wp0 + ci*15;
      const float* rp = &rowp[ci*172 + wv0*5];
      #pragma unroll
      for (int t=0;t<15;t++){
        float wt = wp[t];
        #pragma unroll
        for (int j=0;j<8;j++) acc[j] += rp[j*5 + t]*wt;
      }
    }
    #pragma unroll
    for (int j=0;j<8;j++) y1s[co][wv0+j] = lrelu(acc[j]);
  }
  __syncthreads();
  const int oc = tid;
  const int kk = oc >> 6, c = oc & 63;
  float a2[32];
  #pragma unroll
  for (int wv=0;wv<32;wv++) a2[wv]=0.f;
  const float* wp = we2 + (size_t)oc*64;
  for (int ci=0; ci<64; ci++){
    float wt = wp[ci];
    const float* yp = &y1s[ci][0];
    #pragma unroll
    for (int wv=0; wv<32; wv++) a2[wv] += yp[wv]*wt;
  }
  if (!VERT){
    float* dst = out + (size_t)(b*64+c)*25600 + hw*160 + kk;
    #pragma unroll
    for (int wv=0; wv<32; wv++) dst[wv*5] = lrelu(a2[wv]);
  } else {
    float* dst = out + (size_t)(b*64+c)*25600 + kk*160 + hw;
    #pragma unroll
    for (int wv=0; wv<32; wv++) dst[wv*800] = lrelu(a2[wv]);
  }
}

// ---------------- pass A: per-branch sums ---------------------------------
__global__ __launch_bounds__(256) void k_redA(const float* __restrict__ b0, const float* __restrict__ b1,
                                              const float* __restrict__ b2, const float* __restrict__ b3,
                                              float* __restrict__ part){
  const int b = blockIdx.y, blk = blockIdx.x;
  const int tid = threadIdx.x;
  const size_t off = (size_t)b*1638400 + (size_t)blk*25600;
  float s0=0,s1=0,s2=0,s3=0;
  for (int it=0; it<100; it++){
    int m = it*256 + tid;
    s0 += b0[off+m]; s1 += b1[off+m]; s2 += b2[off+m]; s3 += b3[off+m];
  }
  float vals[4] = {s0,s1,s2,s3};
  __shared__ float red[4][4];
  int lane = tid & 63, wv = tid >> 6;
  #pragma unroll
  for (int j=0;j<4;j++){
    float v = vals[j];
    #pragma unroll
    for (int o=32;o>0;o>>=1) v += __shfl_down(v,o,64);
    if (lane==0) red[wv][j]=v;
  }
  __syncthreads();
  if (tid<4) part[((size_t)b*64+blk)*16 + tid] = red[0][tid]+red[1][tid]+red[2][tid]+red[3][tid];
}

// ---------------- means ----------------------------------------------------
__global__ void k_mean(const float* __restrict__ part, float* __restrict__ mu){
  const int b = blockIdx.x, tid = threadIdx.x;
  if (tid<4){
    float t=0;
    for (int blk=0;blk<64;blk++) t += part[((size_t)b*64+blk)*16 + tid];
    mu[b*4+tid] = t / 1638400.f;
  }
}

// ---------------- pass B: centered covariance products --------------------
__global__ __launch_bounds__(256) void k_redB(const float* __restrict__ b0, const float* __restrict__ b1,
                                              const float* __restrict__ b2, const float* __restrict__ b3,
                                              const float* __restrict__ mu, float* __restrict__ part2){
  const int b = blockIdx.y, blk = blockIdx.x;
  const int tid = threadIdx.x;
  const size_t off = (size_t)b*1638400 + (size_t)blk*25600;
  const float m0=mu[b*4+0], m1=mu[b*4+1], m2=mu[b*4+2], m3=mu[b*4+3];
  float p00=0,p01=0,p02=0,p03=0,p11=0,p12=0,p13=0,p22=0,p23=0,p33=0;
  for (int it=0; it<100; it++){
    int m = it*256 + tid;
    float x0 = b0[off+m]-m0;
    float x1 = b1[off+m]-m1;
    float x2 = b2[off+m]-m2;
    float x3 = b3[off+m]-m3;
    p00+=x0*x0; p01+=x0*x1; p02+=x0*x2; p03+=x0*x3;
    p11+=x1*x1; p12+=x1*x2; p13+=x1*x3;
    p22+=x2*x2; p23+=x2*x3; p33+=x3*x3;
  }
  float vals[10] = {p00,p01,p02,p03,p11,p12,p13,p22,p23,p33};
  __shared__ float red[4][10];
  int lane = tid & 63, wv = tid >> 6;
  #pragma unroll
  for (int j=0;j<10;j++){
    float v = vals[j];
    #pragma unroll
    for (int o=32;o>0;o>>=1) v += __shfl_down(v,o,64);
    if (lane==0) red[wv][j]=v;
  }
  __syncthreads();
  if (tid<10) part2[((size_t)b*64+blk)*16 + tid] = red[0][tid]+red[1][tid]+red[2][tid]+red[3][tid];
}

// ---- finalize att (4x4) and fold attention einsum + identity into fuse1 weights
// Weff[co][k*64+c] = wf1[co][k*64+c] + sum_n att[n][k] * wf1[co][n*64+c]   (R4==R5 verified equal)
__global__ __launch_bounds__(256) void k_attW(const float* __restrict__ part2,
        const float* __restrict__ alpha, const float* __restrict__ gamma, const float* __restrict__ beta,
        int iblk, const float* __restrict__ wf1, float* __restrict__ Weff){
  const int b = blockIdx.x, tid = threadIdx.x;
  __shared__ float st[10];
  __shared__ float att[16];
  if (tid<10){
    float t=0;
    for (int blk=0;blk<64;blk++) t += part2[((size_t)b*64+blk)*16 + tid];
    st[tid]=t;
  }
  __syncthreads();
  if (tid==0){
    const float M = 1638400.f;
    float S[4][4];
    S[0][0]=st[0]; S[0][1]=S[1][0]=st[1]; S[0][2]=S[2][0]=st[2]; S[0][3]=S[3][0]=st[3];
    S[1][1]=st[4]; S[1][2]=S[2][1]=st[5]; S[1][3]=S[3][1]=st[6];
    S[2][2]=st[7]; S[2][3]=S[3][2]=st[8]; S[3][3]=st[9];
    float al=alpha[iblk], ga=gamma[iblk], be=beta[iblk];
    float scale = al/(M-1.f);
    float cov[4][4], ss=0.f;
    for (int n=0;n<4;n++) for (int k=0;k<4;k++){
      float c = S[n][k]*scale;
      cov[n][k]=c; ss += c*c;
    }
    float rms = sqrtf(ss/16.f + 1e-5f);
    for (int n=0;n<4;n++) for (int k=0;k<4;k++){
      float g = ga*cov[n][k]/rms + be;
      att[n*4+k] = g/(1.f+expf(-g));   // g*sigmoid(g)
    }
  }
  __syncthreads();
  for (int idx=tid; idx<16384; idx+=256){
    int co=idx>>8, kc=idx&255, k=kc>>6, c=kc&63;
    float v = wf1[co*256+kc];
    #pragma unroll
    for (int n=0;n<4;n++) v += att[n*4+k]*wf1[co*256+n*64+c];
    Weff[(size_t)b*16384+idx] = v;
  }
}

// ---------------- fuse1: per-batch GEMM 64x256 @ 256x25600 with Weff, lrelu
// y64 written IN-PLACE over b0 (each block reads only its own px columns, then writes them)
__global__ __launch_bounds__(256) void k_fuse1(const float* b0, const float* __restrict__ b1,
                                               const float* __restrict__ b2, const float* __restrict__ b3,
                                               const float* __restrict__ Weff, float* y64){
  const int tile = blockIdx.x, b = blockIdx.y;
  const int px0 = tile*64;
  const int tid = threadIdx.x;
  const int ti = tid >> 4, tj = tid & 15;
  __shared__ float xs[64][65];
  __shared__ float wsh[64][65];
  float acc[4][4];
  #pragma unroll
  for (int i=0;i<4;i++)
    #pragma unroll
    for (int j=0;j<4;j++) acc[i][j]=0.f;
  const float* bptr[4] = {b0,b1,b2,b3};
  for (int kb=0; kb<4; kb++){
    const float* xbk = bptr[kb] + (size_t)b*1638400 + px0;
    const float* wb = Weff + (size_t)b*16384 + kb*64;
    __syncthreads();
    for (int idx=tid; idx<4096; idx+=256){
      int kc=idx>>6, px=idx&63;
      xs[kc][px] = xbk[(size_t)kc*25600 + px];
    }
    for (int idx=tid; idx<4096; idx+=256){
      int co=idx>>6, k2=idx&63;
      wsh[co][k2] = wb[co*256 + k2];
    }
    __syncthreads();
    for (int k2=0;k2<64;k2++){
      float a0=wsh[ti][k2], a1=wsh[ti+16][k2], a2=wsh[ti+32][k2], a3=wsh[ti+48][k2];
      float v0=xs[k2][tj], v1=xs[k2][tj+16], v2=xs[k2][tj+32], v3=xs[k2][tj+48];
      acc[0][0]+=a0*v0; acc[0][1]+=a0*v1; acc[0][2]+=a0*v2; acc[0][3]+=a0*v3;
      acc[1][0]+=a1*v0; acc[1][1]+=a1*v1; acc[1][2]+=a1*v2; acc[1][3]+=a1*v3;
      acc[2][0]+=a2*v0; acc[2][1]+=a2*v1; acc[2][2]+=a2*v2; acc[2][3]+=a2*v3;
      acc[3][0]+=a3*v0; acc[3][1]+=a3*v1; acc[3][2]+=a3*v2; acc[3][3]+=a3*v3;
    }
  }
  #pragma unroll
  for (int ii=0;ii<4;ii++)
    #pragma unroll
    for (int jj=0;jj<4;jj++){
      int co = ti + ii*16, px = tj + jj*16;
      y64[((size_t)b*64+co)*25600 + px0 + px] = lrelu(acc[ii][jj]);
    }
}

// ---------------- fuse2: dilated 3x3 (dil 5, pad 5) + residual + mac2sai --
// grid (B*25, 8 cogroups of 8), block 256. Interior tiles skip bounds checks.
// mac2sai (reference-literal): flat = hh*800 + ww*25 + a_i*5 + a_j
template<int FINAL>
__global__ __launch_bounds__(256) void k_fuse2(const float* __restrict__ y64, const float* resid,
                                               const float* __restrict__ w, float* outA,
                                               float* outB1, float* dout){
  const int b = blockIdx.x / 25, tile = blockIdx.x % 25;
  const int th0 = (tile/5)*32, tw0 = (tile%5)*32;
  const int cog = blockIdx.y;
  const int tid = threadIdx.x;
  const bool interior = (th0>=32 && th0<=96 && tw0>=32 && tw0<=96);
  __shared__ float plane[42*48];
  __shared__ float wl[72];
  float acc[4][8];
  #pragma unroll
  for (int k=0;k<4;k++)
    #pragma unroll
    for (int c=0;c<8;c++) acc[k][c]=0.f;
  const float* src = y64 + (size_t)b*1638400;
  for (int ci=0; ci<64; ci++){
    __syncthreads();
    if (interior){
      const float* s0 = src + (size_t)ci*25600 + (th0-5)*160 + (tw0-5);
      for (int idx=tid; idx<42*42; idx+=256){
        int r = idx/42, cc = idx - r*42;
        plane[r*48+cc] = s0[r*160 + cc];
      }
    } else {
      for (int idx=tid; idx<42*42; idx+=256){
        int r = idx/42, cc = idx - r*42;
        int gh = th0 + r - 5, gw = tw0 + cc - 5;
        float v = 0.f;
        if ((unsigned)gh < 160u && (unsigned)gw < 160u) v = src[(size_t)ci*25600 + gh*160 + gw];
        plane[r*48+cc] = v;
      }
    }
    if (tid<72) wl[tid] = w[((size_t)(cog*8 + tid/9)*64 + ci)*9 + tid%9];
    __syncthreads();
    #pragma unroll
    for (int k=0;k<4;k++){
      int p = tid + k*256;
      int si = p >> 5, sj = p & 31;
      const float* pp = &plane[si*48 + sj];
      float n0=pp[0],   n1=pp[5],   n2=pp[10];
      float n3=pp[240], n4=pp[245], n5=pp[250];
      float n6=pp[480], n7=pp[485], n8=pp[490];
      #pragma unroll
      for (int c=0;c<8;c++){
        const float* wp=&wl[c*9];
        acc[k][c] += n0*wp[0]+n1*wp[1]+n2*wp[2]+n3*wp[3]+n4*wp[4]+n5*wp[5]+n6*wp[6]+n7*wp[7]+n8*wp[8];
      }
    }
  }
  #pragma unroll
  for (int k=0;k<4;k++){
    int p = tid + k*256;
    int si = p >> 5, sj = p & 31;
    int h = th0 + si, wq = tw0 + sj;
    #pragma unroll
    for (int c=0;c<8;c++){
      int cg = cog*8 + c;
      size_t base = ((size_t)(b*64+cg)*160 + h)*160 + wq;
      float v = acc[k][c] + resid[base];
      if (FINAL){
        dout[base] = v;
      } else {
        outA[base] = v;
        size_t m2s = (size_t)(b*64+cg)*25600 + (size_t)(h&31)*800 + (wq&31)*25 + (h>>5)*5 + (wq>>5);
        outB1[m2s] = v;
      }
    }
  }
}

extern "C" void kernel_launch(void* const* d_in, const int* in_sizes, int n_in,
                              void* d_out, int out_size, void* d_ws, size_t ws_size,
                              hipStream_t stream){
  const float* x    = (const float*)d_in[0];
  const float* x1   = (const float*)d_in[1];
  const float* wspa = (const float*)d_in[2];
  const float* wang = (const float*)d_in[3];
  const float* we1  = (const float*)d_in[4];
  const float* we2  = (const float*)d_in[5];
  const float* al   = (const float*)d_in[6];
  const float* ga   = (const float*)d_in[7];
  const float* be   = (const float*)d_in[8];
  const float* wf1  = (const float*)d_in[9];
  const float* wf2  = (const float*)d_in[10];

  char* ws = (char*)d_ws;
  const size_t SLOT = 26214400;
  float* A  = (float*)(ws);          // MacPI buf (in-place residual chain)
  float* Bv = (float*)(ws +   SLOT); // SAI buf / branchV (rotates with T2)
  float* T1 = (float*)(ws + 2*SLOT); // branchSpa, then y64 in-place
  float* T2 = (float*)(ws + 3*SLOT); // branchAng, then newB1
  float* part  = (float*)(ws + 4*SLOT);            // 4*64*16 f32
  float* part2 = (float*)(ws + 4*SLOT + 16384);    // 4*64*16 f32
  float* mu    = (float*)(ws + 4*SLOT + 32768);    // 16 f32
  float* Weff  = (float*)(ws + 4*SLOT + 33280);    // 4*64*256 f32
  float* D = (float*)d_out;          // branchH scratch; final output at the end

  for (int i=0;i<4;i++){
    const float* Asrc  = (i==0) ? x  : (const float*)A;
    const float* B1src = (i==0) ? x1 : (const float*)Bv;
    k_spa<<<dim3(100,8),256,0,stream>>>(B1src, wspa + (size_t)i*36864, T1);
    k_ang<<<dim3(128,8),256,0,stream>>>(Asrc,  wang + (size_t)i*36864, T2);
    k_epi<0><<<640,320,0,stream>>>(Asrc, we1 + (size_t)i*61440, we2 + (size_t)i*20480, D);
    k_epi<1><<<640,320,0,stream>>>(Asrc, we1 + (size_t)i*61440, we2 + (size_t)i*20480, Bv);
    k_redA<<<dim3(64,4),256,0,stream>>>(T1, T2, D, Bv, part);
    k_mean<<<4,64,0,stream>>>(part, mu);
    k_redB<<<dim3(64,4),256,0,stream>>>(T1, T2, D, Bv, mu, part2);
    k_attW<<<4,256,0,stream>>>(part2, al, ga, be, i, wf1 + (size_t)i*16384, Weff);
    k_fuse1<<<dim3(400,4),256,0,stream>>>(T1, T2, D, Bv, Weff, T1);
    if (i<3){
      k_fuse2<0><<<dim3(100,8),256,0,stream>>>(T1, Asrc, wf2 + (size_t)i*36864, A, T2, nullptr);
      float* t = Bv; Bv = T2; T2 = t;
    } else {
      k_fuse2<1><<<dim3(100,8),256,0,stream>>>(T1, Asrc, wf2 + (size_t)i*36864, nullptr, nullptr, D);
    }
  }
}

// Round 8
// 3567.536 us; speedup vs baseline: 1.5279x; 1.5279x over previous
//
#include <hip/hip_runtime.h>
#include <hip/hip_bf16.h>

__device__ __forceinline__ float lrelu(float v){ return v >= 0.f ? v : 0.1f*v; }

// Dims: B=4, C=64, H=W=160, HW=25600, per-tensor (B,64,160,160) f32: batch stride 1,638,400
// ws: 4 f32 slots x 26,214,400 B (A, Bv, T1, T2) + part/Weff tail. branchH lives in d_out.
// Per iter: epiV->T2(tmp), spa->T1, permV T2->Bv, ang->T2, epiH->D, red, attW,
//           fuse1->T1(inplace), fuse2->A (or dout), permM A->Bv.

// ---------------- spa: per-view 3x3 conv (zero pad at view edges) ----------
// grid (B*25, 8 cogroups of 8co). Weights via wave-uniform global loads (s_load).
__global__ __launch_bounds__(256) void k_spa(const float* __restrict__ buf1, const float* __restrict__ w,
                                             float* __restrict__ out){
  const int b = blockIdx.x / 25, view = blockIdx.x % 25;
  const int bi = view / 5, bj = view % 5;
  const int cog = blockIdx.y;
  const int tid = threadIdx.x;
  __shared__ float plane[34*40];   // interior rows 1..32, cols 4..35; border stays 0
  for (int idx=tid; idx<34*40; idx+=256) plane[idx]=0.f;
  float acc[4][8];
  #pragma unroll
  for (int k=0;k<4;k++)
    #pragma unroll
    for (int c=0;c<8;c++) acc[k][c]=0.f;
  const float* src = buf1 + (size_t)b*1638400 + bi*32*160 + bj*32;
  const float* wb = w + (size_t)(cog*8)*576;   // [co][ci][9]
  const int r = tid >> 3, qc = (tid & 7)*4;
  for (int ci=0; ci<64; ci++){
    __syncthreads();
    *(float4*)&plane[(1+r)*40 + 4 + qc] = *(const float4*)(src + (size_t)ci*25600 + r*160 + qc);
    __syncthreads();
    float t[4][9];
    #pragma unroll
    for (int k=0;k<4;k++){
      int p = tid + k*256;
      const float* pp = &plane[(p>>5)*40 + (p&31) + 3];
      t[k][0]=pp[0];  t[k][1]=pp[1];  t[k][2]=pp[2];
      t[k][3]=pp[40]; t[k][4]=pp[41]; t[k][5]=pp[42];
      t[k][6]=pp[80]; t[k][7]=pp[81]; t[k][8]=pp[82];
    }
    #pragma unroll
    for (int c=0;c<8;c++){
      const float* wp = wb + (size_t)c*576 + ci*9;   // uniform -> s_load
      float w0=wp[0],w1=wp[1],w2=wp[2],w3=wp[3],w4=wp[4],w5=wp[5],w6=wp[6],w7=wp[7],w8=wp[8];
      #pragma unroll
      for (int k=0;k<4;k++)
        acc[k][c] += t[k][0]*w0+t[k][1]*w1+t[k][2]*w2+t[k][3]*w3+t[k][4]*w4
                   + t[k][5]*w5+t[k][6]*w6+t[k][7]*w7+t[k][8]*w8;
    }
  }
  #pragma unroll
  for (int k=0;k<4;k++){
    int p = tid + k*256;
    int si = p >> 5, sj = p & 31;
    int h = si*5 + bi, wq = sj*5 + bj;
    #pragma unroll
    for (int c=0;c<8;c++){
      int ch = b*64 + cog*8 + c;
      out[(size_t)ch*25600 + h*160 + wq] = lrelu(acc[k][c]);
    }
  }
}

// ---------------- ang: per-macropixel (5x5) 3x3 conv ----------------------
__global__ __launch_bounds__(256) void k_ang(const float* __restrict__ bufA, const float* __restrict__ w,
                                             float* __restrict__ out){
  const int b = blockIdx.x >> 5, mi = blockIdx.x & 31;
  const int cog = blockIdx.y;
  const int tid = threadIdx.x;
  __shared__ float rowp[7*172];    // rows 0,6 zero guards; data cols 4..163
  for (int idx=tid; idx<7*172; idx+=256) rowp[idx]=0.f;
  float acc[4][8];
  #pragma unroll
  for (int k=0;k<4;k++)
    #pragma unroll
    for (int c=0;c<8;c++) acc[k][c]=0.f;
  int pu[4], pbase[4];
  float plm[4], prm[4];
  bool act[4];
  #pragma unroll
  for (int k=0;k<4;k++){
    int p = tid + k*256;
    act[k] = p < 800;
    int pp = act[k] ? p : 0;
    int mp = pp/25; int pos = pp - mp*25;
    int u = pos/5, v = pos - u*5;
    pu[k] = u; pbase[k] = 4 + mp*5 + v - 1;
    plm[k] = (v!=0) ? 1.f : 0.f;
    prm[k] = (v!=4) ? 1.f : 0.f;
  }
  const float* src = bufA + (size_t)b*1638400 + mi*800;
  const float* wb = w + (size_t)(cog*8)*576;
  const int sr = tid/40, sq = (tid%40)*4;
  for (int ci=0; ci<64; ci++){
    __syncthreads();
    if (tid < 200)
      *(float4*)&rowp[(1+sr)*172 + 4 + sq] = *(const float4*)(src + (size_t)ci*25600 + sr*160 + sq);
    __syncthreads();
    float t[4][9];
    #pragma unroll
    for (int k=0;k<4;k++){
      if (act[k]){
        const float* pp = &rowp[pu[k]*172 + pbase[k]];
        float lm=plm[k], rm=prm[k];
        t[k][0]=pp[0]*lm;   t[k][1]=pp[1];   t[k][2]=pp[2]*rm;
        t[k][3]=pp[172]*lm; t[k][4]=pp[173]; t[k][5]=pp[174]*rm;
        t[k][6]=pp[344]*lm; t[k][7]=pp[345]; t[k][8]=pp[346]*rm;
      } else {
        #pragma unroll
        for (int j=0;j<9;j++) t[k][j]=0.f;
      }
    }
    #pragma unroll
    for (int c=0;c<8;c++){
      const float* wp = wb + (size_t)c*576 + ci*9;
      float w0=wp[0],w1=wp[1],w2=wp[2],w3=wp[3],w4=wp[4],w5=wp[5],w6=wp[6],w7=wp[7],w8=wp[8];
      #pragma unroll
      for (int k=0;k<4;k++)
        acc[k][c] += t[k][0]*w0+t[k][1]*w1+t[k][2]*w2+t[k][3]*w3+t[k][4]*w4
                   + t[k][5]*w5+t[k][6]*w6+t[k][7]*w7+t[k][8]*w8;
    }
  }
  #pragma unroll
  for (int k=0;k<4;k++){
    if (act[k]){
      int p = tid + k*256;
      int mp = p/25; int pos = p - mp*25;
      int u = pos/5, v = pos - u*5;
      int h = mi*5 + u, wq = mp*5 + v;
      #pragma unroll
      for (int c=0;c<8;c++){
        int ch = b*64 + cog*8 + c;
        out[(size_t)ch*25600 + h*160 + wq] = lrelu(acc[k][c]);
      }
    }
  }
}

// ---------------- fused EPI: [1,15]s5p5 + lrelu + 1x1 64->320 + shuffle ---
// Output routed through LDS -> coalesced 160-float row writes.
// VERT=0: out = branchH final layout. VERT=1: out = tmp[(b,c),hw,r] (transposed later).
template<int VERT>
__global__ __launch_bounds__(320) void k_epi(const float* __restrict__ bufA, const float* __restrict__ we1,
                                             const float* __restrict__ we2, float* __restrict__ out){
  const int b = blockIdx.x / 160, hw = blockIdx.x % 160;
  const int tid = threadIdx.x;
  __shared__ float rowp[64*176];   // data at [8,168); zeros [0,8) & [168,176). Reused as y2s.
  __shared__ float y1s[64*32];
  // stage
  if (VERT){
    for (int idx=tid; idx<10240; idx+=320){
      int ci = idx/160, x = idx - ci*160;
      rowp[ci*176 + 8 + x] = bufA[(size_t)b*1638400 + (size_t)ci*25600 + (size_t)x*160 + hw];
    }
  } else {
    for (int ft=tid; ft<2560; ft+=320){
      int ci = ft/40, xq = (ft - ci*40)*4;
      *(float4*)&rowp[ci*176 + 8 + xq] =
        *(const float4*)(bufA + (size_t)b*1638400 + (size_t)ci*25600 + (size_t)hw*160 + xq);
    }
  }
  for (int idx=tid; idx<64*16; idx+=320){
    int ci = idx>>4, j = idx&15;
    rowp[ci*176 + (j<8 ? j : 160+j)] = 0.f;
  }
  __syncthreads();
  // conv1: windows wv, taps at lds idx 3 + wv*5 + t (data offset 8, pad 5)
  if (tid < 256){
    const int co = tid >> 2, wv0 = (tid & 3)*8;
    const int a0 = 2 + wv0*5;                 // even -> float2-aligned
    float acc[8];
    #pragma unroll
    for (int j=0;j<8;j++) acc[j]=0.f;
    const float* wp0 = we1 + (size_t)co*960;
    for (int ci=0; ci<64; ci++){
      float fl[52];
      const float* rp = &rowp[ci*176 + a0];
      #pragma unroll
      for (int m=0;m<26;m++) *(float2*)&fl[2*m] = *(const float2*)&rp[2*m];
      const float* wp = wp0 + ci*15;
      #pragma unroll
      for (int t=0;t<15;t++){
        float wt = wp[t];
        #pragma unroll
        for (int j=0;j<8;j++) acc[j] += fl[1 + j*5 + t]*wt;
      }
    }
    #pragma unroll
    for (int j=0;j<8;j++) y1s[co*32 + wv0 + j] = lrelu(acc[j]);
  }
  __syncthreads();
  // conv2 1x1 64->320, pixel shuffle into y2s (alias rowp): y2s[c*160 + wv*5 + kk]
  {
    const int oc = tid, kk = oc >> 6, c = oc & 63;
    float a2[32];
    #pragma unroll
    for (int wv=0;wv<32;wv++) a2[wv]=0.f;
    const float* wp = we2 + (size_t)oc*64;
    for (int ci=0; ci<64; ci++){
      float wt = wp[ci];
      const float* yp = &y1s[ci*32];
      #pragma unroll
      for (int wv=0; wv<32; wv++) a2[wv] += yp[wv]*wt;
    }
    float* y2s = rowp;
    #pragma unroll
    for (int wv=0; wv<32; wv++) y2s[c*160 + wv*5 + kk] = lrelu(a2[wv]);
  }
  __syncthreads();
  // coalesced writeout: rows of 160 per channel
  {
    const float* y2s = rowp;
    for (int k=0;k<8;k++){
      int f = (tid + k*320)*4;               // < 40960
      int c = f/160, rr = f - c*160;
      *(float4*)(out + (size_t)(b*64+c)*25600 + (size_t)hw*160 + rr) = *(const float4*)&y2s[c*160+rr];
    }
  }
}

// ---------------- permV: per-(b,c) 160x160 transpose tmp[hw][r] -> Bv[r][hw]
__global__ __launch_bounds__(256) void k_permV(const float* __restrict__ tmp, float* __restrict__ dst){
  const int bc = blockIdx.x;
  const int ti = blockIdx.y / 5, tj = blockIdx.y % 5;
  const int hw0 = ti*32, r0 = tj*32;
  const int lx = threadIdx.x & 31, ly = threadIdx.x >> 5;   // 32 x 8
  __shared__ float tile[32][33];
  const float* in = tmp + (size_t)bc*25600;
  float* outp = dst + (size_t)bc*25600;
  for (int yy=ly; yy<32; yy+=8)
    tile[yy][lx] = in[(size_t)(hw0+yy)*160 + r0 + lx];
  __syncthreads();
  for (int yy=ly; yy<32; yy+=8)
    outp[(size_t)(r0+yy)*160 + hw0 + lx] = tile[lx][yy];
}

// ---------------- permM: mac2sai  newB1[f] = A[ai*32+hh][aj*32+ww], f=hh*800+ww*25+ai*5+aj
__global__ __launch_bounds__(256) void k_permM(const float* __restrict__ A, float* __restrict__ dst){
  const int bc = blockIdx.x >> 5, hh = blockIdx.x & 31;
  const int tid = threadIdx.x;
  __shared__ float rows[5*160];
  const float* in = A + (size_t)bc*25600;
  if (tid < 200){
    int ai = tid/40, q = (tid - ai*40)*4;
    *(float4*)&rows[ai*160 + q] = *(const float4*)(in + (size_t)(ai*32+hh)*160 + q);
  }
  __syncthreads();
  float* outp = dst + (size_t)bc*25600 + (size_t)hh*800;
  for (int t=tid; t<800; t+=256){
    int ww = t/25, r2 = t - ww*25, ai = r2/5, aj = r2 - ai*5;
    outp[t] = rows[ai*160 + aj*32 + ww];
  }
}

// ---------------- single-pass stats: 4 sums + 10 products (E-formula) -----
__global__ __launch_bounds__(256) void k_red(const float* __restrict__ b0, const float* __restrict__ b1,
                                             const float* __restrict__ b2, const float* __restrict__ b3,
                                             float* __restrict__ part){
  const int b = blockIdx.y, blk = blockIdx.x;
  const int tid = threadIdx.x;
  const size_t off = (size_t)b*1638400 + (size_t)blk*25600;
  float s0=0,s1=0,s2=0,s3=0;
  float p00=0,p01=0,p02=0,p03=0,p11=0,p12=0,p13=0,p22=0,p23=0,p33=0;
  for (int it=0; it<25; it++){
    size_t m = off + it*1024 + tid*4;
    float4 x0 = *(const float4*)(b0+m);
    float4 x1 = *(const float4*)(b1+m);
    float4 x2 = *(const float4*)(b2+m);
    float4 x3 = *(const float4*)(b3+m);
    s0 += (x0.x+x0.y)+(x0.z+x0.w);
    s1 += (x1.x+x1.y)+(x1.z+x1.w);
    s2 += (x2.x+x2.y)+(x2.z+x2.w);
    s3 += (x3.x+x3.y)+(x3.z+x3.w);
    p00 += x0.x*x0.x+x0.y*x0.y+x0.z*x0.z+x0.w*x0.w;
    p01 += x0.x*x1.x+x0.y*x1.y+x0.z*x1.z+x0.w*x1.w;
    p02 += x0.x*x2.x+x0.y*x2.y+x0.z*x2.z+x0.w*x2.w;
    p03 += x0.x*x3.x+x0.y*x3.y+x0.z*x3.z+x0.w*x3.w;
    p11 += x1.x*x1.x+x1.y*x1.y+x1.z*x1.z+x1.w*x1.w;
    p12 += x1.x*x2.x+x1.y*x2.y+x1.z*x2.z+x1.w*x2.w;
    p13 += x1.x*x3.x+x1.y*x3.y+x1.z*x3.z+x1.w*x3.w;
    p22 += x2.x*x2.x+x2.y*x2.y+x2.z*x2.z+x2.w*x2.w;
    p23 += x2.x*x3.x+x2.y*x3.y+x2.z*x3.z+x2.w*x3.w;
    p33 += x3.x*x3.x+x3.y*x3.y+x3.z*x3.z+x3.w*x3.w;
  }
  float vals[14] = {s0,s1,s2,s3,p00,p01,p02,p03,p11,p12,p13,p22,p23,p33};
  __shared__ float red[4][14];
  int lane = tid & 63, wv = tid >> 6;
  #pragma unroll
  for (int j=0;j<14;j++){
    float v = vals[j];
    #pragma unroll
    for (int o=32;o>0;o>>=1) v += __shfl_down(v,o,64);
    if (lane==0) red[wv][j]=v;
  }
  __syncthreads();
  if (tid<14) part[((size_t)b*64+blk)*16 + tid] = red[0][tid]+red[1][tid]+red[2][tid]+red[3][tid];
}

// ---- att (4x4) via E-formula, fold attention + identity into fuse1 weights
__global__ __launch_bounds__(256) void k_attW(const float* __restrict__ part,
        const float* __restrict__ alpha, const float* __restrict__ gamma, const float* __restrict__ beta,
        int iblk, const float* __restrict__ wf1, float* __restrict__ Weff){
  const int b = blockIdx.x, tid = threadIdx.x;
  __shared__ float st[14];
  __shared__ float att[16];
  if (tid<14){
    float t=0;
    for (int blk=0;blk<64;blk++) t += part[((size_t)b*64+blk)*16 + tid];
    st[tid]=t;
  }
  __syncthreads();
  if (tid==0){
    const float M = 1638400.f;
    float s[4] = {st[0],st[1],st[2],st[3]};
    float S[4][4];
    S[0][0]=st[4];  S[0][1]=S[1][0]=st[5];  S[0][2]=S[2][0]=st[6];  S[0][3]=S[3][0]=st[7];
    S[1][1]=st[8];  S[1][2]=S[2][1]=st[9];  S[1][3]=S[3][1]=st[10];
    S[2][2]=st[11]; S[2][3]=S[3][2]=st[12]; S[3][3]=st[13];
    float al=alpha[iblk], ga=gamma[iblk], be=beta[iblk];
    float scale = al/(M-1.f);
    float cov[4][4], ss=0.f;
    for (int n=0;n<4;n++) for (int k=0;k<4;k++){
      float c = (S[n][k] - s[n]*s[k]/M)*scale;
      cov[n][k]=c; ss += c*c;
    }
    float rms = sqrtf(ss/16.f + 1e-5f);
    for (int n=0;n<4;n++) for (int k=0;k<4;k++){
      float g = ga*cov[n][k]/rms + be;
      att[n*4+k] = g/(1.f+expf(-g));
    }
  }
  __syncthreads();
  for (int idx=tid; idx<16384; idx+=256){
    int co=idx>>8, kc=idx&255, k=kc>>6, c=kc&63;
    float v = wf1[co*256+kc];
    #pragma unroll
    for (int n=0;n<4;n++) v += att[n*4+k]*wf1[co*256+n*64+c];
    Weff[(size_t)b*16384+idx] = v;
  }
}

// ---------------- fuse1: per-batch GEMM 64x256 @ 256x25600, float4-blocked
__global__ __launch_bounds__(256) void k_fuse1(const float* b0, const float* __restrict__ b1,
                                               const float* __restrict__ b2, const float* __restrict__ b3,
                                               const float* __restrict__ Weff, float* y64){
  const int tile = blockIdx.x, b = blockIdx.y;
  const int px0 = tile*64;
  const int tid = threadIdx.x;
  const int ti = tid >> 4, tj = tid & 15;      // co = ti*4.., px = tj*4..
  __shared__ float xs[64][68];                 // [k2][px]
  __shared__ float wt[64][68];                 // [k2][co]
  float acc[4][4];
  #pragma unroll
  for (int i=0;i<4;i++)
    #pragma unroll
    for (int j=0;j<4;j++) acc[i][j]=0.f;
  const float* bptr[4] = {b0,b1,b2,b3};
  for (int kb=0; kb<4; kb++){
    const float* xbk = bptr[kb] + (size_t)b*1638400 + px0;
    const float* wb = Weff + (size_t)b*16384 + kb*64;
    __syncthreads();
    for (int idx=tid; idx<4096; idx+=256){
      int kc=idx>>6, px=idx&63;
      xs[kc][px] = xbk[(size_t)kc*25600 + px];
    }
    for (int idx=tid; idx<4096; idx+=256){
      int co=idx>>6, k2=idx&63;
      wt[k2][co] = wb[co*256 + k2];
    }
    __syncthreads();
    for (int k2=0;k2<64;k2++){
      float4 a = *(const float4*)&wt[k2][ti*4];
      float4 v = *(const float4*)&xs[k2][tj*4];
      acc[0][0]+=a.x*v.x; acc[0][1]+=a.x*v.y; acc[0][2]+=a.x*v.z; acc[0][3]+=a.x*v.w;
      acc[1][0]+=a.y*v.x; acc[1][1]+=a.y*v.y; acc[1][2]+=a.y*v.z; acc[1][3]+=a.y*v.w;
      acc[2][0]+=a.z*v.x; acc[2][1]+=a.z*v.y; acc[2][2]+=a.z*v.z; acc[2][3]+=a.z*v.w;
      acc[3][0]+=a.w*v.x; acc[3][1]+=a.w*v.y; acc[3][2]+=a.w*v.z; acc[3][3]+=a.w*v.w;
    }
  }
  #pragma unroll
  for (int i=0;i<4;i++){
    int co = ti*4 + i;
    float4 o = make_float4(lrelu(acc[i][0]), lrelu(acc[i][1]), lrelu(acc[i][2]), lrelu(acc[i][3]));
    *(float4*)(y64 + ((size_t)(b*64+co))*25600 + px0 + tj*4) = o;
  }
}

// ---------------- fuse2: dilated 3x3 (dil 5, pad 5) + residual ------------
template<int FINAL>
__global__ __launch_bounds__(256) void k_fuse2(const float* __restrict__ y64, const float* resid,
                                               const float* __restrict__ w, float* outp){
  const int b = blockIdx.x / 25, tile = blockIdx.x % 25;
  const int th0 = (tile/5)*32, tw0 = (tile%5)*32;
  const int cog = blockIdx.y;
  const int tid = threadIdx.x;
  const bool interior = (th0>=32 && th0<=96 && tw0>=32 && tw0<=96);
  __shared__ float plane[42*48];
  float acc[4][8];
  #pragma unroll
  for (int k=0;k<4;k++)
    #pragma unroll
    for (int c=0;c<8;c++) acc[k][c]=0.f;
  const float* src = y64 + (size_t)b*1638400;
  const float* wb = w + (size_t)(cog*8)*576;
  for (int ci=0; ci<64; ci++){
    __syncthreads();
    if (interior){
      const float* s0 = src + (size_t)ci*25600 + (th0-5)*160 + (tw0-5);
      for (int idx=tid; idx<42*42; idx+=256){
        int r = idx/42, cc = idx - r*42;
        plane[r*48+cc] = s0[r*160 + cc];
      }
    } else {
      for (int idx=tid; idx<42*42; idx+=256){
        int r = idx/42, cc = idx - r*42;
        int gh = th0 + r - 5, gw = tw0 + cc - 5;
        float v = 0.f;
        if ((unsigned)gh < 160u && (unsigned)gw < 160u) v = src[(size_t)ci*25600 + gh*160 + gw];
        plane[r*48+cc] = v;
      }
    }
    __syncthreads();
    float t[4][9];
    #pragma unroll
    for (int k=0;k<4;k++){
      int p = tid + k*256;
      const float* pp = &plane[(p>>5)*48 + (p&31)];
      t[k][0]=pp[0];   t[k][1]=pp[5];   t[k][2]=pp[10];
      t[k][3]=pp[240]; t[k][4]=pp[245]; t[k][5]=pp[250];
      t[k][6]=pp[480]; t[k][7]=pp[485]; t[k][8]=pp[490];
    }
    #pragma unroll
    for (int c=0;c<8;c++){
      const float* wp = wb + (size_t)c*576 + ci*9;
      float w0=wp[0],w1=wp[1],w2=wp[2],w3=wp[3],w4=wp[4],w5=wp[5],w6=wp[6],w7=wp[7],w8=wp[8];
      #pragma unroll
      for (int k=0;k<4;k++)
        acc[k][c] += t[k][0]*w0+t[k][1]*w1+t[k][2]*w2+t[k][3]*w3+t[k][4]*w4
                   + t[k][5]*w5+t[k][6]*w6+t[k][7]*w7+t[k][8]*w8;
    }
  }
  #pragma unroll
  for (int k=0;k<4;k++){
    int p = tid + k*256;
    int si = p >> 5, sj = p & 31;
    int h = th0 + si, wq = tw0 + sj;
    #pragma unroll
    for (int c=0;c<8;c++){
      int cg = cog*8 + c;
      size_t base = ((size_t)(b*64+cg)*160 + h)*160 + wq;
      outp[base] = acc[k][c] + resid[base];
    }
  }
}

extern "C" void kernel_launch(void* const* d_in, const int* in_sizes, int n_in,
                              void* d_out, int out_size, void* d_ws, size_t ws_size,
                              hipStream_t stream){
  const float* x    = (const float*)d_in[0];
  const float* x1   = (const float*)d_in[1];
  const float* wspa = (const float*)d_in[2];
  const float* wang = (const float*)d_in[3];
  const float* we1  = (const float*)d_in[4];
  const float* we2  = (const float*)d_in[5];
  const float* al   = (const float*)d_in[6];
  const float* ga   = (const float*)d_in[7];
  const float* be   = (const float*)d_in[8];
  const float* wf1  = (const float*)d_in[9];
  const float* wf2  = (const float*)d_in[10];

  char* ws = (char*)d_ws;
  const size_t SLOT = 26214400;
  float* A  = (float*)(ws);          // MacPI buf (in-place residual chain)
  float* Bv = (float*)(ws +   SLOT); // B1 input / branchV / newB1
  float* T1 = (float*)(ws + 2*SLOT); // branchSpa -> y64 in-place
  float* T2 = (float*)(ws + 3*SLOT); // epiV tmp -> branchAng
  float* part = (float*)(ws + 4*SLOT);            // 4*64*16 f32
  float* Weff = (float*)(ws + 4*SLOT + 16384);    // 4*64*256 f32
  float* D = (float*)d_out;          // branchH scratch; final output at the end

  for (int i=0;i<4;i++){
    const float* Asrc  = (i==0) ? x  : (const float*)A;
    const float* B1src = (i==0) ? x1 : (const float*)Bv;
    k_epi<1><<<640,320,0,stream>>>(Asrc, we1 + (size_t)i*61440, we2 + (size_t)i*20480, T2);
    k_spa<<<dim3(100,8),256,0,stream>>>(B1src, wspa + (size_t)i*36864, T1);
    k_permV<<<dim3(256,25),256,0,stream>>>(T2, Bv);
    k_ang<<<dim3(128,8),256,0,stream>>>(Asrc, wang + (size_t)i*36864, T2);
    k_epi<0><<<640,320,0,stream>>>(Asrc, we1 + (size_t)i*61440, we2 + (size_t)i*20480, D);
    k_red<<<dim3(64,4),256,0,stream>>>(T1, T2, D, Bv, part);
    k_attW<<<4,256,0,stream>>>(part, al, ga, be, i, wf1 + (size_t)i*16384, Weff);
    k_fuse1<<<dim3(400,4),256,0,stream>>>(T1, T2, D, Bv, Weff, T1);
    if (i<3){
      k_fuse2<0><<<dim3(100,8),256,0,stream>>>(T1, Asrc, wf2 + (size_t)i*36864, A);
      k_permM<<<8192,256,0,stream>>>(A, Bv);
    } else {
      k_fuse2<1><<<dim3(100,8),256,0,stream>>>(T1, Asrc, wf2 + (size_t)i*36864, D);
    }
  }
}